// Round 1
// baseline (2159.448 us; speedup 1.0000x reference)
//
#include <hip/hip_runtime.h>
#include <hip/hip_bf16.h>

// Problem constants
#define N_NODES 10000
#define N_EDGES 128000
constexpr int C = 128;
constexpr int A = 10;

constexpr float INV_SQRT_C  = 0.08838834764831845f;   // 1/sqrt(128)
constexpr float INV_SQRT_R  = 0.35355339059327373f;   // 1/sqrt(8)
constexpr float INV_SQRT_64 = 0.125f;                 // 1/sqrt(64)
constexpr float INV_SQRT_CA = 0.027950849718747374f;  // 1/sqrt(1280)
constexpr float INV_SQRT_2C = 0.0625f;                // 1/sqrt(256)
constexpr float INV_SQRT_3  = 0.57735026918962576f;

__device__ __forceinline__ float silu_f(float x) { return x / (1.0f + __expf(-x)); }

__device__ __forceinline__ void atomic_add_f32(float* p, float v) {
  __hip_atomic_fetch_add(p, v, __ATOMIC_RELAXED, __HIP_MEMORY_SCOPE_AGENT);
}

// ---------------------------------------------------------------------------
// K1: H[n, u*4+0] = h0[n,u],  H[n, u*4+1+k] = h1[n,u,k]
// h0 = x0 @ W_up0 / sqrt(C); h1[:,:,k] = x1[:,:,k] @ W_up1 / sqrt(C)
// Block: 256 threads, 8 nodes. g = t>>7 picks node-half, v = t&127.
// ---------------------------------------------------------------------------
__global__ __launch_bounds__(256) void k_node_up(
    const float* __restrict__ nf, const float* __restrict__ Wu0,
    const float* __restrict__ Wu1, float* __restrict__ H) {
  __shared__ __align__(16) float xs[8][C][4];  // [nn][u][{x0,x1_0,x1_1,x1_2}]
  const int t = threadIdx.x;
  const int n0 = blockIdx.x * 8;
  for (int idx = t; idx < 8 * 512; idx += 256) {
    const int nn = idx >> 9, q = idx & 511;
    const float val = nf[(size_t)(n0 + nn) * 512 + q];
    if (q < C) xs[nn][q][0] = val;
    else { const int r = q - C; xs[nn][r / 3][1 + r % 3] = val; }
  }
  __syncthreads();
  const int g = t >> 7, v = t & 127;
  float acc[4][4] = {};
  for (int u = 0; u < C; ++u) {
    const float w0 = Wu0[u * C + v];
    const float w1 = Wu1[u * C + v];
#pragma unroll
    for (int nn = 0; nn < 4; ++nn) {
      const float4 xv = *(const float4*)&xs[g * 4 + nn][u][0];
      acc[nn][0] = fmaf(xv.x, w0, acc[nn][0]);
      acc[nn][1] = fmaf(xv.y, w1, acc[nn][1]);
      acc[nn][2] = fmaf(xv.z, w1, acc[nn][2]);
      acc[nn][3] = fmaf(xv.w, w1, acc[nn][3]);
    }
  }
#pragma unroll
  for (int nn = 0; nn < 4; ++nn) {
    const int n = n0 + g * 4 + nn;
    float4 o;
    o.x = acc[nn][0] * INV_SQRT_C; o.y = acc[nn][1] * INV_SQRT_C;
    o.z = acc[nn][2] * INV_SQRT_C; o.w = acc[nn][3] * INV_SQRT_C;
    *(float4*)&H[(size_t)n * 512 + v * 4] = o;
  }
}

// ---------------------------------------------------------------------------
// K2: skip connection sc -> written directly into d_out (second output).
// sc0[n,v] = sum_{u,a} x0[n,u]*attr[n,a]*Ws0[u,a,v] / sqrt(C*A)
// sc1[n,v,k] likewise with x1, Ws1. Out row: [sc0 (128) | sc1 flat v*3+k (384)]
// ---------------------------------------------------------------------------
__global__ __launch_bounds__(256) void k_skip(
    const float* __restrict__ nf, const float* __restrict__ attrs,
    const float* __restrict__ Ws0, const float* __restrict__ Ws1,
    float* __restrict__ sc_out) {
  __shared__ __align__(16) float xs[8][C][4];
  __shared__ float at[8][A];
  const int t = threadIdx.x;
  const int n0 = blockIdx.x * 8;
  for (int idx = t; idx < 8 * 512; idx += 256) {
    const int nn = idx >> 9, q = idx & 511;
    const float val = nf[(size_t)(n0 + nn) * 512 + q];
    if (q < C) xs[nn][q][0] = val;
    else { const int r = q - C; xs[nn][r / 3][1 + r % 3] = val; }
  }
  for (int idx = t; idx < 8 * A; idx += 256)
    at[idx / A][idx % A] = attrs[(size_t)(n0 + idx / A) * A + idx % A];
  __syncthreads();
  const int g = t >> 7, v = t & 127;
  float acc[4][4] = {};
  for (int u0 = 0; u0 < C; u0 += 4) {
    float4 xv[4][4];  // register-cache x so the a-loop doesn't re-read LDS
#pragma unroll
    for (int nn = 0; nn < 4; ++nn)
#pragma unroll
      for (int j = 0; j < 4; ++j)
        xv[nn][j] = *(const float4*)&xs[g * 4 + nn][u0 + j][0];
#pragma unroll 2
    for (int a = 0; a < A; ++a) {
      float aa[4];
#pragma unroll
      for (int nn = 0; nn < 4; ++nn) aa[nn] = at[g * 4 + nn][a];
#pragma unroll
      for (int j = 0; j < 4; ++j) {
        const float w0 = Ws0[((u0 + j) * A + a) * C + v];
        const float w1 = Ws1[((u0 + j) * A + a) * C + v];
#pragma unroll
        for (int nn = 0; nn < 4; ++nn) {
          const float t0 = aa[nn] * w0;
          const float t1 = aa[nn] * w1;
          acc[nn][0] = fmaf(xv[nn][j].x, t0, acc[nn][0]);
          acc[nn][1] = fmaf(xv[nn][j].y, t1, acc[nn][1]);
          acc[nn][2] = fmaf(xv[nn][j].z, t1, acc[nn][2]);
          acc[nn][3] = fmaf(xv[nn][j].w, t1, acc[nn][3]);
        }
      }
    }
  }
#pragma unroll
  for (int nn = 0; nn < 4; ++nn) {
    const int n = n0 + g * 4 + nn;
    float* row = sc_out + (size_t)n * 512;
    row[v]             = acc[nn][0] * INV_SQRT_CA;
    row[C + v * 3 + 0] = acc[nn][1] * INV_SQRT_CA;
    row[C + v * 3 + 1] = acc[nn][2] * INV_SQRT_CA;
    row[C + v * 3 + 2] = acc[nn][3] * INV_SQRT_CA;
  }
}

// ---------------------------------------------------------------------------
// K3: per-edge MLP (8->64->64->64->512, silu on first 3), density, gather H,
// form messages, atomic scatter into M[n][p][j] (p<128: m0a/m1a; p>=128:
// m0b/m1b; j=0 -> M0, j=1+k -> M1[...,k]).
// Block: 256 threads, 16 edges.
// ---------------------------------------------------------------------------
__global__ __launch_bounds__(256) void k_edge(
    const float* __restrict__ ef_g, const float* __restrict__ ea_g,
    const int* __restrict__ eidx,
    const float* __restrict__ R0, const float* __restrict__ R1,
    const float* __restrict__ R2, const float* __restrict__ R3,
    const float* __restrict__ Wd,
    const float* __restrict__ H, float* __restrict__ M,
    float* __restrict__ density) {
  __shared__ __align__(16) float ef[16][8];
  __shared__ __align__(16) float b0[16][64];
  __shared__ __align__(16) float b1[16][64];
  __shared__ __align__(16) float wls[16][512];
  __shared__ float yls[16][4];
  __shared__ int snd[16], rcv[16];
  const int t = threadIdx.x;
  const int e0 = blockIdx.x * 16;

  if (t < 128) ef[t >> 3][t & 7] = ef_g[(size_t)e0 * 8 + t];
  if (t >= 128 && t < 192) { const int i = t - 128; yls[i >> 2][i & 3] = ea_g[(size_t)e0 * 4 + i]; }
  if (t >= 192 && t < 208) snd[t - 192] = eidx[e0 + (t - 192)];
  if (t >= 208 && t < 224) rcv[t - 208] = eidx[N_EDGES + e0 + (t - 208)];
  __syncthreads();

  // density contribution (one thread per edge)
  if (t < 16) {
    float s = 0.f;
#pragma unroll
    for (int i = 0; i < 8; ++i) s = fmaf(ef[t][i], Wd[i], s);
    s *= INV_SQRT_R;
    atomic_add_f32(&density[rcv[t]], tanhf(s * s));
  }

  // L1: 8 -> 64
  {
    const int j = t & 63;
#pragma unroll
    for (int r = 0; r < 4; ++r) {
      const int e = (t >> 6) + r * 4;
      float s = 0.f;
#pragma unroll
      for (int i = 0; i < 8; ++i) s = fmaf(ef[e][i], R0[i * 64 + j], s);
      b0[e][j] = silu_f(s * INV_SQRT_R);
    }
  }
  __syncthreads();

  // L2: 64 -> 64 (b0 -> b1)
  {
    const int e = t >> 4, jg = t & 15;
    float acc[4] = {};
    for (int i0 = 0; i0 < 64; i0 += 4) {
      const float4 b = *(const float4*)&b0[e][i0];
#pragma unroll
      for (int ii = 0; ii < 4; ++ii) {
        const float bv = (&b.x)[ii];
#pragma unroll
        for (int q = 0; q < 4; ++q)
          acc[q] = fmaf(bv, R1[(i0 + ii) * 64 + jg + 16 * q], acc[q]);
      }
    }
#pragma unroll
    for (int q = 0; q < 4; ++q) b1[e][jg + 16 * q] = silu_f(acc[q] * INV_SQRT_64);
  }
  __syncthreads();

  // L3: 64 -> 64 (b1 -> b0)
  {
    const int e = t >> 4, jg = t & 15;
    float acc[4] = {};
    for (int i0 = 0; i0 < 64; i0 += 4) {
      const float4 b = *(const float4*)&b1[e][i0];
#pragma unroll
      for (int ii = 0; ii < 4; ++ii) {
        const float bv = (&b.x)[ii];
#pragma unroll
        for (int q = 0; q < 4; ++q)
          acc[q] = fmaf(bv, R2[(i0 + ii) * 64 + jg + 16 * q], acc[q]);
      }
    }
    __syncthreads();  // b0 still being read above in other threads' L3? No: all read b1. Safe to wait once here before overwrite.
#pragma unroll
    for (int q = 0; q < 4; ++q) b0[e][jg + 16 * q] = silu_f(acc[q] * INV_SQRT_64);
  }
  __syncthreads();

  // L4: 64 -> 512, no silu. eg = t>>7 handles 8 edges; j = (t&127)*4 + q.
  {
    const int eg = t >> 7;
    const int jg = t & 127;
    float wacc[8][4] = {};
    for (int i0 = 0; i0 < 64; i0 += 4) {
      float4 bb[8];
#pragma unroll
      for (int e = 0; e < 8; ++e) bb[e] = *(const float4*)&b0[eg * 8 + e][i0];
#pragma unroll
      for (int ii = 0; ii < 4; ++ii) {
        const float4 r4 = *(const float4*)&R3[(size_t)(i0 + ii) * 512 + jg * 4];
#pragma unroll
        for (int e = 0; e < 8; ++e) {
          const float bv = (&bb[e].x)[ii];
          wacc[e][0] = fmaf(bv, r4.x, wacc[e][0]);
          wacc[e][1] = fmaf(bv, r4.y, wacc[e][1]);
          wacc[e][2] = fmaf(bv, r4.z, wacc[e][2]);
          wacc[e][3] = fmaf(bv, r4.w, wacc[e][3]);
        }
      }
    }
#pragma unroll
    for (int e = 0; e < 8; ++e) {
      float4 o;
      o.x = wacc[e][0] * INV_SQRT_64; o.y = wacc[e][1] * INV_SQRT_64;
      o.z = wacc[e][2] * INV_SQRT_64; o.w = wacc[e][3] * INV_SQRT_64;
      *(float4*)&wls[eg * 8 + e][jg * 4] = o;
    }
  }
  __syncthreads();

  // Messages + atomic scatter. Two edges in flight: sub = t>>7, u = t&127.
  const int sub = t >> 7, u = t & 127;
#pragma unroll 1
  for (int ep = 0; ep < 8; ++ep) {
    const int e = ep * 2 + sub;
    const int s = snd[e], n = rcv[e];
    const float4 h4 = *(const float4*)&H[(size_t)s * 512 + u * 4];
    const float w1v = wls[e][u], w2v = wls[e][C + u];
    const float w3v = wls[e][2 * C + u], w4v = wls[e][3 * C + u];
    const float y0 = yls[e][0];
    const float y1x = yls[e][1], y1y = yls[e][2], y1z = yls[e][3];
    const float hs0 = h4.x;
    const float dt = h4.y * y1x + h4.z * y1y + h4.w * y1z;
    float* Mn = &M[(size_t)n * 1024];
    atomic_add_f32(&Mn[u * 4 + 0], w1v * hs0 * y0);
    const float c1 = w2v * hs0;
    atomic_add_f32(&Mn[u * 4 + 1], c1 * y1x);
    atomic_add_f32(&Mn[u * 4 + 2], c1 * y1y);
    atomic_add_f32(&Mn[u * 4 + 3], c1 * y1z);
    atomic_add_f32(&Mn[512 + u * 4 + 0], w4v * dt * INV_SQRT_3);
    const float c3 = w3v * y0;
    atomic_add_f32(&Mn[512 + u * 4 + 1], c3 * h4.y);
    atomic_add_f32(&Mn[512 + u * 4 + 2], c3 * h4.z);
    atomic_add_f32(&Mn[512 + u * 4 + 3], c3 * h4.w);
  }
}

// ---------------------------------------------------------------------------
// K4: out0 = M0 @ Wl0 /16/denom; out1[.,.,k] = M1[...,k] @ Wl1 /16/denom
// message[n,v,0]=out0, message[n,v,1+k]=out1 -> float4 store per (n,v).
// ---------------------------------------------------------------------------
__global__ __launch_bounds__(256) void k_out(
    const float* __restrict__ M, const float* __restrict__ density,
    const float* __restrict__ Wl0, const float* __restrict__ Wl1,
    float* __restrict__ out) {
  __shared__ __align__(16) float Ms[8][256][4];  // 32 KB
  __shared__ float dens[8];
  const int t = threadIdx.x;
  const int n0 = blockIdx.x * 8;
  const float4* Msrc = (const float4*)&M[(size_t)n0 * 1024];
  float4* Mdst = (float4*)&Ms[0][0][0];
  for (int idx = t; idx < 8 * 256; idx += 256) Mdst[idx] = Msrc[idx];
  if (t < 8) dens[t] = density[n0 + t] + 1.0f;
  __syncthreads();
  const int g = t >> 7, v = t & 127;
  float acc[4][4] = {};
  for (int p0 = 0; p0 < 256; p0 += 4) {
    float4 mv[4][4];
#pragma unroll
    for (int nn = 0; nn < 4; ++nn)
#pragma unroll
      for (int j = 0; j < 4; ++j)
        mv[nn][j] = *(const float4*)&Ms[g * 4 + nn][p0 + j][0];
#pragma unroll
    for (int j = 0; j < 4; ++j) {
      const float w0 = Wl0[(p0 + j) * C + v];
      const float w1 = Wl1[(p0 + j) * C + v];
#pragma unroll
      for (int nn = 0; nn < 4; ++nn) {
        acc[nn][0] = fmaf(mv[nn][j].x, w0, acc[nn][0]);
        acc[nn][1] = fmaf(mv[nn][j].y, w1, acc[nn][1]);
        acc[nn][2] = fmaf(mv[nn][j].z, w1, acc[nn][2]);
        acc[nn][3] = fmaf(mv[nn][j].w, w1, acc[nn][3]);
      }
    }
  }
#pragma unroll
  for (int nn = 0; nn < 4; ++nn) {
    const int n = n0 + g * 4 + nn;
    const float sc = INV_SQRT_2C / dens[g * 4 + nn];
    float4 o;
    o.x = acc[nn][0] * sc; o.y = acc[nn][1] * sc;
    o.z = acc[nn][2] * sc; o.w = acc[nn][3] * sc;
    *(float4*)&out[(size_t)n * 512 + v * 4] = o;
  }
}

// ---------------------------------------------------------------------------
extern "C" void kernel_launch(void* const* d_in, const int* in_sizes, int n_in,
                              void* d_out, int out_size, void* d_ws, size_t ws_size,
                              hipStream_t stream) {
  const float* node_attrs = (const float*)d_in[0];
  const float* node_feats = (const float*)d_in[1];
  const float* edge_attrs = (const float*)d_in[2];
  const float* edge_feats = (const float*)d_in[3];
  const int*   edge_index = (const int*)d_in[4];
  const float* W_up0 = (const float*)d_in[5];
  const float* W_up1 = (const float*)d_in[6];
  const float* R0 = (const float*)d_in[7];
  const float* R1 = (const float*)d_in[8];
  const float* R2 = (const float*)d_in[9];
  const float* R3 = (const float*)d_in[10];
  const float* Wd  = (const float*)d_in[11];
  const float* Wl0 = (const float*)d_in[12];
  const float* Wl1 = (const float*)d_in[13];
  const float* Ws0 = (const float*)d_in[14];
  const float* Ws1 = (const float*)d_in[15];
  float* out = (float*)d_out;

  // Workspace: H (N*512) | M (N*1024) | density (N)   -> ~61.5 MB
  float* H = (float*)d_ws;
  float* M = H + (size_t)N_NODES * 512;
  float* density = M + (size_t)N_NODES * 1024;

  // zero M + density (contiguous)
  hipMemsetAsync(M, 0, (size_t)(N_NODES * 1024 + N_NODES) * sizeof(float), stream);

  k_node_up<<<N_NODES / 8, 256, 0, stream>>>(node_feats, W_up0, W_up1, H);
  k_skip<<<N_NODES / 8, 256, 0, stream>>>(node_feats, node_attrs, Ws0, Ws1,
                                          out + (size_t)N_NODES * 512);
  k_edge<<<N_EDGES / 16, 256, 0, stream>>>(edge_feats, edge_attrs, edge_index,
                                           R0, R1, R2, R3, Wd, H, M, density);
  k_out<<<N_NODES / 8, 256, 0, stream>>>(M, density, Wl0, Wl1, out);
}